// Round 1
// baseline (22179.819 us; speedup 1.0000x reference)
//
#include <hip/hip_runtime.h>
#include <hip/hip_bf16.h>

#define TT 512
#define BB 256
#define II 64
#define HH 256

typedef _Float16 half8 __attribute__((ext_vector_type(8)));
typedef float f32x4 __attribute__((ext_vector_type(4)));

__device__ __forceinline__ float sigm(float x) {
    return 1.0f / (1.0f + __expf(-x));
}
__device__ __forceinline__ float tanhfast(float x) {
    float e = __expf(2.0f * x);
    return 1.0f - 2.0f / (e + 1.0f);
}
__device__ __forceinline__ half8 cvt8(const float* p) {
    half8 r;
#pragma unroll
    for (int i = 0; i < 8; ++i) r[i] = (_Float16)p[i];
    return r;
}

// Persistent fused 2-layer LSTM + MLP head.
// Grid: 16 workgroups (one per 16-row batch slice), 1024 threads = 16 waves.
// Wave w owns gate-channel slice [w*16, w*16+16) => gate rows q*256+w*16+c.
// All recurrent weights live in per-wave VGPR fragments (f16), loaded once.
__global__ __launch_bounds__(1024, 1) void lstm_persist(
    const float* __restrict__ x,
    const float* __restrict__ Wih0, const float* __restrict__ Whh0,
    const float* __restrict__ bih0, const float* __restrict__ bhh0,
    const float* __restrict__ Wih1, const float* __restrict__ Whh1,
    const float* __restrict__ bih1, const float* __restrict__ bhh1,
    const float* __restrict__ W1, const float* __restrict__ b1,
    const float* __restrict__ W2, const float* __restrict__ b2,
    float* __restrict__ out)
{
    // buf0 row: [h0 (256) | x_t (64) | pad (8)]  stride 328 halves = 656 B
    // buf1 row: [h1 (256) | pad (8)]             stride 264 halves = 528 B
    __shared__ __align__(16) _Float16 sb0[2][16][328];
    __shared__ __align__(16) _Float16 sb1[2][16][264];
    __shared__ __align__(16) float zsh[16][128];

    const int tid = threadIdx.x;
    const int w   = tid >> 6;   // wave 0..15
    const int l   = tid & 63;   // lane
    const int lr  = l & 15;     // row/col within MFMA tile
    const int lk  = l >> 4;     // k-subgroup 0..3
    const int wgb = blockIdx.x * 16;  // batch base

    // ---- load weight fragments into registers (once) ----
    // Fragment (q,k): lane holds W[n][k*32 + lk*8 .. +7], n = q*256 + w*16 + lr.
    // MFMA B-operand layout: lane = (k/8)*16 + n, elems = 8 consecutive k.
    half8 w0[4][10];   // layer0: k<8 -> Whh0, k=8,9 -> Wih0   (K = 256+64)
    half8 w1f[4][16];  // layer1: k<8 -> Whh1, k>=8 -> Wih1    (K = 256+256)
    float bias0[4], bias1[4];
#pragma unroll
    for (int q = 0; q < 4; ++q) {
        const int n = q * HH + w * 16 + lr;
#pragma unroll
        for (int k = 0; k < 10; ++k) {
            const float* src = (k < 8) ? (Whh0 + n * 256 + k * 32 + lk * 8)
                                       : (Wih0 + n * 64 + (k - 8) * 32 + lk * 8);
            w0[q][k] = cvt8(src);
        }
#pragma unroll
        for (int k = 0; k < 16; ++k) {
            const float* src = (k < 8) ? (Whh1 + n * 256 + k * 32 + lk * 8)
                                       : (Wih1 + n * 256 + (k - 8) * 32 + lk * 8);
            w1f[q][k] = cvt8(src);
        }
        bias0[q] = bih0[n] + bhh0[n];
        bias1[q] = bih1[n] + bhh1[n];
    }

    // ---- init LDS: h0[-1]=0 (+x region), h1[-1]=0 ----
    {
        _Float16* f0 = &sb0[0][0][0];
        for (int idx = tid; idx < 16 * 328; idx += 1024) f0[idx] = (_Float16)0.0f;
        _Float16* f1 = &sb1[0][0][0];
        for (int idx = tid; idx < 16 * 264; idx += 1024) f1[idx] = (_Float16)0.0f;
    }
    __syncthreads();
    // stage x_0 into sb0[0] x-region: wave w -> batch row w, lane l -> feature l
    sb0[0][w][256 + l] = (_Float16)x[(size_t)(wgb + w) * (TT * II) + l];
    __syncthreads();

    float c0s[4] = {0.f, 0.f, 0.f, 0.f};
    float c1s[4] = {0.f, 0.f, 0.f, 0.f};

    for (int t = 0; t < TT; ++t) {
        const int cur = t & 1, nxt = cur ^ 1;
        const _Float16* A0 = &sb0[cur][0][0];
        _Float16*       D0 = &sb0[nxt][0][0];
        const _Float16* A1 = &sb1[cur][0][0];
        _Float16*       D1 = &sb1[nxt][0][0];

        // ======== layer 0: gates = [h0(t-1); x_t] @ [Whh0,Wih0]^T + b ========
        f32x4 acc[4];
#pragma unroll
        for (int q = 0; q < 4; ++q) {
            acc[q][0] = bias0[q]; acc[q][1] = bias0[q];
            acc[q][2] = bias0[q]; acc[q][3] = bias0[q];
        }
#pragma unroll
        for (int k = 0; k < 10; ++k) {
            half8 a = *(const half8*)(A0 + lr * 328 + k * 32 + lk * 8);
#pragma unroll
            for (int q = 0; q < 4; ++q)
                acc[q] = __builtin_amdgcn_mfma_f32_16x16x32_f16(a, w0[q][k], acc[q], 0, 0, 0);
        }
        // C/D layout: col = lane&15 (channel), row = lk*4 + j (batch row)
#pragma unroll
        for (int j = 0; j < 4; ++j) {
            float ig = sigm(acc[0][j]);
            float fg = sigm(acc[1][j]);
            float gg = tanhfast(acc[2][j]);
            float og = sigm(acc[3][j]);
            float c  = fg * c0s[j] + ig * gg;
            c0s[j] = c;
            float h = og * tanhfast(c);
            D0[(lk * 4 + j) * 328 + w * 16 + lr] = (_Float16)h;
        }
        __syncthreads();

        // ======== layer 1: gates = [h1(t-1); h0(t)] @ [Whh1,Wih1]^T + b ======
#pragma unroll
        for (int q = 0; q < 4; ++q) {
            acc[q][0] = bias1[q]; acc[q][1] = bias1[q];
            acc[q][2] = bias1[q]; acc[q][3] = bias1[q];
        }
#pragma unroll
        for (int k = 0; k < 8; ++k) {
            half8 a = *(const half8*)(A1 + lr * 264 + k * 32 + lk * 8);
#pragma unroll
            for (int q = 0; q < 4; ++q)
                acc[q] = __builtin_amdgcn_mfma_f32_16x16x32_f16(a, w1f[q][k], acc[q], 0, 0, 0);
        }
#pragma unroll
        for (int k = 8; k < 16; ++k) {
            half8 a = *(const half8*)(D0 + lr * 328 + (k - 8) * 32 + lk * 8);
#pragma unroll
            for (int q = 0; q < 4; ++q)
                acc[q] = __builtin_amdgcn_mfma_f32_16x16x32_f16(a, w1f[q][k], acc[q], 0, 0, 0);
        }
#pragma unroll
        for (int j = 0; j < 4; ++j) {
            float ig = sigm(acc[0][j]);
            float fg = sigm(acc[1][j]);
            float gg = tanhfast(acc[2][j]);
            float og = sigm(acc[3][j]);
            float c  = fg * c1s[j] + ig * gg;
            c1s[j] = c;
            float h = og * tanhfast(c);
            D1[(lk * 4 + j) * 264 + w * 16 + lr] = (_Float16)h;
        }
        // prefetch x_{t+1} into D0 (= sb0[(t+1)&1]) x-region; disjoint from
        // the h-region reads above, covered by the end-of-step barrier.
        if (t + 1 < TT) {
            D0[w * 328 + 256 + l] =
                (_Float16)x[(size_t)(wgb + w) * (TT * II) + (t + 1) * II + l];
        }
        __syncthreads();
    }

    // ======== epilogue: out = tanh(h1_last @ W1^T + b1) @ W2^T + b2 ========
    // h1_last sits in sb1[TT & 1] == sb1[0]
    for (int idx = tid; idx < 16 * 128; idx += 1024) {
        const int r = idx >> 7, j = idx & 127;
        float s = b1[j];
        const _Float16* hrow = &sb1[0][r][0];
        const float* wrow = W1 + j * 256;
        for (int k = 0; k < 256; ++k) s += (float)hrow[k] * wrow[k];
        zsh[r][j] = tanhfast(s);
    }
    __syncthreads();
    for (int idx = tid; idx < 16 * 96; idx += 1024) {
        const int r = idx / 96, o = idx - r * 96;
        float s = b2[o];
        const float* wrow = W2 + o * 128;
        for (int k = 0; k < 128; ++k) s += zsh[r][k] * wrow[k];
        out[(size_t)(wgb + r) * 96 + o] = s;
    }
}

extern "C" void kernel_launch(void* const* d_in, const int* in_sizes, int n_in,
                              void* d_out, int out_size, void* d_ws, size_t ws_size,
                              hipStream_t stream) {
    const float* x    = (const float*)d_in[0];
    const float* Wih0 = (const float*)d_in[1];
    const float* Whh0 = (const float*)d_in[2];
    const float* bih0 = (const float*)d_in[3];
    const float* bhh0 = (const float*)d_in[4];
    const float* Wih1 = (const float*)d_in[5];
    const float* Whh1 = (const float*)d_in[6];
    const float* bih1 = (const float*)d_in[7];
    const float* bhh1 = (const float*)d_in[8];
    const float* W1   = (const float*)d_in[9];
    const float* b1   = (const float*)d_in[10];
    const float* W2   = (const float*)d_in[11];
    const float* b2   = (const float*)d_in[12];

    hipLaunchKernelGGL(lstm_persist, dim3(16), dim3(1024), 0, stream,
                       x, Wih0, Whh0, bih0, bhh0,
                       Wih1, Whh1, bih1, bhh1,
                       W1, b1, W2, b2, (float*)d_out);
}

// Round 2
// 5826.932 us; speedup vs baseline: 3.8064x; 3.8064x over previous
//
#include <hip/hip_runtime.h>
#include <hip/hip_bf16.h>

#define TT 512
#define II 64
#define HH 256
#define NG 16   // batch groups (16 rows each)
#define NS 8    // gate slices per group

typedef _Float16 half8 __attribute__((ext_vector_type(8)));
typedef float f32x4 __attribute__((ext_vector_type(4)));

__device__ __forceinline__ float sigm(float x){ return 1.0f/(1.0f+__expf(-x)); }
__device__ __forceinline__ float tanhf_(float x){ float e=__expf(2.0f*x); return 1.0f-2.0f/(e+1.0f); }

__device__ __forceinline__ half8 cvt8(const float* __restrict__ p){
    half8 r;
#pragma unroll
    for (int i=0;i<8;++i) r[i]=(_Float16)p[i];
    return r;
}

#define MFMA(A,B,C) __builtin_amdgcn_mfma_f32_16x16x32_f16((A),(B),(C),0,0,0)

// Persistent gate-sliced 2-layer LSTM.
// grid = 128 WGs: group = blockIdx%16 (16 batch rows), slice = blockIdx/16 (32 h-channels).
// Weights (f16 A-fragments) live in VGPRs: 208/wave. h exchanged via global + flags.
__global__ __launch_bounds__(256,1) void lstm_pers(
    const float* __restrict__ x,
    const float* __restrict__ Wih0, const float* __restrict__ Whh0,
    const float* __restrict__ bih0, const float* __restrict__ bhh0,
    const float* __restrict__ Wih1, const float* __restrict__ Whh1,
    const float* __restrict__ bih1, const float* __restrict__ bhh1,
    const float* __restrict__ W1, const float* __restrict__ b1,
    const float* __restrict__ W2, const float* __restrict__ b2,
    unsigned* __restrict__ flag0, unsigned* __restrict__ flag1,
    _Float16* __restrict__ hb0, _Float16* __restrict__ hb1,
    float* __restrict__ out)
{
    const int tid = threadIdx.x;
    const int w   = tid >> 6;          // wave 0..3
    const int l   = tid & 63;
    const int lr  = l & 15;
    const int lk  = l >> 4;
    const int g   = blockIdx.x & (NG-1);
    const int s   = blockIdx.x >> 4;   // 0..7
    const int gbase = g * 16;
    const int cw  = s*32 + w*8;        // wave channel base

    // ---- resident weight fragments (MFMA A-operand) ----
    // Wave's 32 gate-rows are channel-major: local row r -> channel cw + (r>>2), type r&3.
    // A layout: lane holds row = lr (within tile m), k = kt*32 + lk*8 .. +7.
    half8 wA0[10][2];   // layer0: kt<8 -> Whh0 (K=256), kt=8,9 -> Wih0 (K=64)
    half8 wA1[16][2];   // layer1: kt<8 -> Whh1, kt>=8 -> Wih1
    f32x4 bias0v[2], bias1v[2];
#pragma unroll
    for (int m=0;m<2;++m){
        const int n = (lr&3)*HH + cw + m*4 + (lr>>2);
#pragma unroll
        for (int kt=0;kt<10;++kt){
            const float* src = (kt<8) ? (Whh0 + (size_t)n*HH + kt*32 + lk*8)
                                      : (Wih0 + (size_t)n*II + (kt-8)*32 + lk*8);
            wA0[kt][m] = cvt8(src);
        }
#pragma unroll
        for (int kt=0;kt<16;++kt){
            const float* src = (kt<8) ? (Whh1 + (size_t)n*HH + kt*32 + lk*8)
                                      : (Wih1 + (size_t)n*HH + (kt-8)*32 + lk*8);
            wA1[kt][m] = cvt8(src);
        }
        const int cD = cw + m*4 + lk;  // D-layout: row=(lk*4+j) -> chan cw+m*4+lk, type j
#pragma unroll
        for (int j=0;j<4;++j){
            bias0v[m][j] = bih0[j*HH+cD] + bhh0[j*HH+cD];
            bias1v[m][j] = bih1[j*HH+cD] + bhh1[j*HH+cD];
        }
    }
    const int cD0 = cw + lk;

    float c0s[2] = {0.f,0.f};
    float c1s[2] = {0.f,0.f};
    unsigned* f0 = flag0 + g*TT;
    unsigned* f1 = flag1 + g*TT;

    for (int t=0;t<TT;++t){
        const int cur = t & 1, prv = cur ^ 1;

        // ========== layer 0: gates = Whh0*h0(t-1) + Wih0*x_t + b ==========
        f32x4 acc0 = bias0v[0], acc1 = bias0v[1];
        if (t > 0){
            const _Float16* H = hb0 + ((size_t)(prv*NG + g)*16)*HH;
#pragma unroll
            for (int kt=0;kt<8;++kt){
                half8 b = *(const half8*)(H + lr*HH + kt*32 + lk*8);
                acc0 = MFMA(wA0[kt][0], b, acc0);
                acc1 = MFMA(wA0[kt][1], b, acc1);
            }
        }
        {
            const float* xp = x + ((size_t)(gbase+lr)*TT + t)*II + lk*8;
            half8 bx0 = cvt8(xp);
            half8 bx1 = cvt8(xp + 32);
            acc0 = MFMA(wA0[8][0], bx0, acc0);
            acc1 = MFMA(wA0[8][1], bx0, acc1);
            acc0 = MFMA(wA0[9][0], bx1, acc0);
            acc1 = MFMA(wA0[9][1], bx1, acc1);
        }
        {
            _Float16* D0 = hb0 + ((size_t)(cur*NG + g)*16)*HH;
            float ig0=sigm(acc0[0]), fg0=sigm(acc0[1]), gg0=tanhf_(acc0[2]), og0=sigm(acc0[3]);
            float c0 = fg0*c0s[0] + ig0*gg0; c0s[0]=c0;
            D0[lr*HH + cD0] = (_Float16)(og0*tanhf_(c0));
            float ig1=sigm(acc1[0]), fg1=sigm(acc1[1]), gg1=tanhf_(acc1[2]), og1=sigm(acc1[3]);
            float c1 = fg1*c0s[1] + ig1*gg1; c0s[1]=c1;
            D0[lr*HH + cD0 + 4] = (_Float16)(og1*tanhf_(c1));
        }
        __syncthreads();
        if (tid==0){
            __builtin_amdgcn_fence(__ATOMIC_RELEASE, "agent");
            __hip_atomic_fetch_add(&f0[t], 1u, __ATOMIC_RELAXED, __HIP_MEMORY_SCOPE_AGENT);
            while (__hip_atomic_load(&f0[t], __ATOMIC_RELAXED, __HIP_MEMORY_SCOPE_AGENT) < NS)
                __builtin_amdgcn_s_sleep(1);
            if (t>0)
                while (__hip_atomic_load(&f1[t-1], __ATOMIC_RELAXED, __HIP_MEMORY_SCOPE_AGENT) < NS)
                    __builtin_amdgcn_s_sleep(1);
            __builtin_amdgcn_fence(__ATOMIC_ACQUIRE, "agent");
        }
        __syncthreads();

        // ========== layer 1: gates = Whh1*h1(t-1) + Wih1*h0(t) + b ==========
        acc0 = bias1v[0]; acc1 = bias1v[1];
        if (t > 0){
            const _Float16* H1 = hb1 + ((size_t)(prv*NG + g)*16)*HH;
#pragma unroll
            for (int kt=0;kt<8;++kt){
                half8 b = *(const half8*)(H1 + lr*HH + kt*32 + lk*8);
                acc0 = MFMA(wA1[kt][0], b, acc0);
                acc1 = MFMA(wA1[kt][1], b, acc1);
            }
        }
        {
            const _Float16* H0c = hb0 + ((size_t)(cur*NG + g)*16)*HH;
#pragma unroll
            for (int kt=8;kt<16;++kt){
                half8 b = *(const half8*)(H0c + lr*HH + (kt-8)*32 + lk*8);
                acc0 = MFMA(wA1[kt][0], b, acc0);
                acc1 = MFMA(wA1[kt][1], b, acc1);
            }
        }
        {
            _Float16* D1 = hb1 + ((size_t)(cur*NG + g)*16)*HH;
            float ig0=sigm(acc0[0]), fg0=sigm(acc0[1]), gg0=tanhf_(acc0[2]), og0=sigm(acc0[3]);
            float c0 = fg0*c1s[0] + ig0*gg0; c1s[0]=c0;
            D1[lr*HH + cD0] = (_Float16)(og0*tanhf_(c0));
            float ig1=sigm(acc1[0]), fg1=sigm(acc1[1]), gg1=tanhf_(acc1[2]), og1=sigm(acc1[3]);
            float c1 = fg1*c1s[1] + ig1*gg1; c1s[1]=c1;
            D1[lr*HH + cD0 + 4] = (_Float16)(og1*tanhf_(c1));
        }
        __syncthreads();
        if (tid==0){
            __builtin_amdgcn_fence(__ATOMIC_RELEASE, "agent");
            __hip_atomic_fetch_add(&f1[t], 1u, __ATOMIC_RELAXED, __HIP_MEMORY_SCOPE_AGENT);
        }
    }

    // ========== epilogue: MLP head, done by slice 0 of each group ==========
    __shared__ float zsh[16][128];
    if (s == 0){
        if (tid==0){
            while (__hip_atomic_load(&f1[TT-1], __ATOMIC_RELAXED, __HIP_MEMORY_SCOPE_AGENT) < NS)
                __builtin_amdgcn_s_sleep(1);
            __builtin_amdgcn_fence(__ATOMIC_ACQUIRE, "agent");
        }
        __syncthreads();
        const _Float16* hl = hb1 + ((size_t)(((TT-1)&1)*NG + g)*16)*HH;
        for (int idx=tid; idx<16*128; idx+=256){
            const int r = idx>>7, j = idx&127;
            float ssum = b1[j];
            const float* wrow = W1 + j*HH;
            for (int k=0;k<HH;++k) ssum += (float)hl[r*HH+k]*wrow[k];
            zsh[r][j] = tanhf_(ssum);
        }
        __syncthreads();
        for (int idx=tid; idx<16*96; idx+=256){
            const int r = idx/96, o = idx - r*96;
            float ssum = b2[o];
            const float* wrow = W2 + o*128;
            for (int k=0;k<128;++k) ssum += zsh[r][k]*wrow[k];
            out[(size_t)(gbase+r)*96 + o] = ssum;
        }
    }
}

extern "C" void kernel_launch(void* const* d_in, const int* in_sizes, int n_in,
                              void* d_out, int out_size, void* d_ws, size_t ws_size,
                              hipStream_t stream) {
    const float* x    = (const float*)d_in[0];
    const float* Wih0 = (const float*)d_in[1];
    const float* Whh0 = (const float*)d_in[2];
    const float* bih0 = (const float*)d_in[3];
    const float* bhh0 = (const float*)d_in[4];
    const float* Wih1 = (const float*)d_in[5];
    const float* Whh1 = (const float*)d_in[6];
    const float* bih1 = (const float*)d_in[7];
    const float* bhh1 = (const float*)d_in[8];
    const float* W1   = (const float*)d_in[9];
    const float* b1   = (const float*)d_in[10];
    const float* W2   = (const float*)d_in[11];
    const float* b2   = (const float*)d_in[12];

    // workspace: flags (64 KB) | hb0 (256 KB) | hb1 (256 KB)
    unsigned*  flag0 = (unsigned*)d_ws;
    unsigned*  flag1 = flag0 + NG*TT;
    _Float16*  hb0   = (_Float16*)((char*)d_ws + 65536);
    _Float16*  hb1   = hb0 + 2*NG*16*HH;

    hipMemsetAsync(d_ws, 0, 65536, stream);   // zero flags every call (graph-safe)

    hipLaunchKernelGGL(lstm_pers, dim3(NG*NS), dim3(256), 0, stream,
                       x, Wih0, Whh0, bih0, bhh0,
                       Wih1, Whh1, bih1, bhh1,
                       W1, b1, W2, b2,
                       flag0, flag1, hb0, hb1, (float*)d_out);
}

// Round 3
// 3743.285 us; speedup vs baseline: 5.9252x; 1.5566x over previous
//
#include <hip/hip_runtime.h>

#define TT 512
#define II 64
#define HH 256
#define NG 16          // batch groups (16 rows each)
#define NS 8           // gate slices per group (32 channels each)
#define WPG 32u        // waves per group = NS * 4
#define FST 544        // flag stride per group (>= TT+1)

typedef _Float16 half8 __attribute__((ext_vector_type(8)));
typedef float f32x4 __attribute__((ext_vector_type(4)));
typedef float f32x4v __attribute__((ext_vector_type(4)));

__device__ __forceinline__ float sigm(float x){ return 1.0f/(1.0f+__expf(-x)); }
__device__ __forceinline__ float tanhf_(float x){ float e=__expf(2.0f*x); return 1.0f-2.0f/(e+1.0f); }

union HU { _Float16 h; unsigned short u; };
__device__ __forceinline__ unsigned short h2u(float f){ HU x; x.h=(_Float16)f; return x.u; }

__device__ __forceinline__ half8 cvt8v(const float* __restrict__ p){
    f32x4v a = *(const f32x4v*)p, b = *(const f32x4v*)(p+4);
    half8 r;
    r[0]=(_Float16)a[0]; r[1]=(_Float16)a[1]; r[2]=(_Float16)a[2]; r[3]=(_Float16)a[3];
    r[4]=(_Float16)b[0]; r[5]=(_Float16)b[1]; r[6]=(_Float16)b[2]; r[7]=(_Float16)b[3];
    return r;
}

__device__ __forceinline__ void pinreg(half8& v){ asm volatile("" : "+v"(v)); }
__device__ __forceinline__ void pinreg(f32x4& v){ asm volatile("" : "+v"(v)); }

#define MFMA(A,B,C) __builtin_amdgcn_mfma_f32_16x16x32_f16((A),(B),(C),0,0,0)
#define ALOAD64(p)   __hip_atomic_load((p), __ATOMIC_RELAXED, __HIP_MEMORY_SCOPE_AGENT)
#define ASTORE16(p,v) __hip_atomic_store((p), (v), __ATOMIC_RELAXED, __HIP_MEMORY_SCOPE_AGENT)

// Persistent gate-sliced, layer-pipelined 2-layer LSTM.
// 128 WGs x 256 thr: group=blockIdx%16 (16 batch rows), slice=blockIdx/16 (32 chans).
// Superstep t (t=0..TT): compute h0(t) [t<TT] and h1(t-1) [t>0] — both depend only
// on superstep t-1 outputs -> ONE flag per superstep. All cross-WG data moves via
// relaxed agent-scope atomics (cache-bypass, no fences, no L2 wb/inv).
__global__ __launch_bounds__(256,1) __attribute__((amdgpu_waves_per_eu(1)))
void lstm_pers(
    const float* __restrict__ x,
    const float* __restrict__ Wih0, const float* __restrict__ Whh0,
    const float* __restrict__ bih0, const float* __restrict__ bhh0,
    const float* __restrict__ Wih1, const float* __restrict__ Whh1,
    const float* __restrict__ bih1, const float* __restrict__ bhh1,
    const float* __restrict__ W1, const float* __restrict__ b1,
    const float* __restrict__ W2, const float* __restrict__ b2,
    unsigned* __restrict__ flags,
    _Float16* __restrict__ hb0, _Float16* __restrict__ hb1,
    float* __restrict__ out)
{
    // staging: [buf2][tile16][row16][40 halves]; row stride 80B -> 2-way bank alias (free), 16B-aligned
    __shared__ __align__(16) _Float16 stg[2][16][16][40];   // 40 KB

    const int tid = threadIdx.x;
    const int w   = tid >> 6;
    const int l   = tid & 63;
    const int lr  = l & 15;
    const int lk  = l >> 4;
    const int g   = blockIdx.x & (NG-1);
    const int s   = blockIdx.x >> 4;
    const int gbase = g * 16;
    const int cw  = s*32 + w*8;

    // ---- resident weight fragments (MFMA A-operand), pinned in VGPRs ----
    half8 wA0[10][2];   // layer0: kt<8 -> Whh0 (K=256), kt=8,9 -> Wih0 (K=64)
    half8 wA1[16][2];   // layer1: kt<8 -> Whh1, kt>=8 -> Wih1
    f32x4 bias0v[2], bias1v[2];
#pragma unroll
    for (int m=0;m<2;++m){
        const int n = (lr&3)*HH + cw + m*4 + (lr>>2);
#pragma unroll
        for (int kt=0;kt<10;++kt){
            const float* src = (kt<8) ? (Whh0 + (size_t)n*HH + kt*32 + lk*8)
                                      : (Wih0 + (size_t)n*II + (kt-8)*32 + lk*8);
            wA0[kt][m] = cvt8v(src);
            pinreg(wA0[kt][m]);
        }
#pragma unroll
        for (int kt=0;kt<16;++kt){
            const float* src = (kt<8) ? (Whh1 + (size_t)n*HH + kt*32 + lk*8)
                                      : (Wih1 + (size_t)n*HH + (kt-8)*32 + lk*8);
            wA1[kt][m] = cvt8v(src);
            pinreg(wA1[kt][m]);
        }
        const int cD = cw + m*4 + lk;
#pragma unroll
        for (int j=0;j<4;++j){
            bias0v[m][j] = bih0[j*HH+cD] + bhh0[j*HH+cD];
            bias1v[m][j] = bih1[j*HH+cD] + bhh1[j*HH+cD];
        }
        pinreg(bias0v[m]); pinreg(bias1v[m]);
    }
    const int cD0 = cw + lk;

    float c0s0=0.f, c0s1=0.f, c1s0=0.f, c1s1=0.f;
    unsigned* fgrp = flags + g*FST;

    for (int t=0; t<=TT; ++t){
        // ---- cooperative staging: tiles 0..7 = h0(t-1), 8..15 = h1(t-2) ----
        if (t > 0){
            const int ntile = (t >= 2) ? 16 : 8;
            char* sb = (char*)&stg[t&1][0][0][0];
            const unsigned long long* H0 = (const unsigned long long*)hb0
                + ((size_t)(((t-1)&1)*NG + g)*16)*64;
            const unsigned long long* H1 = (const unsigned long long*)hb1
                + ((size_t)((t&1)*NG + g)*16)*64;
#pragma unroll
            for (int i=0;i<8;++i){
                const int uidx = i*256 + tid;
                const int tile = uidx >> 7;
                if (tile < ntile){
                    const int u = uidx & 127, r = u >> 3, q = u & 7;
                    const unsigned long long* srcp = (tile < 8)
                        ? (H0 + (size_t)r*64 + tile*8 + q)
                        : (H1 + (size_t)r*64 + (tile-8)*8 + q);
                    unsigned long long v = ALOAD64(srcp);
                    *(unsigned long long*)(sb + tile*1280 + r*80 + q*8) = v;
                }
            }
        }

        f32x4 a0m0 = bias0v[0], a0m1 = bias0v[1];
        f32x4 a1m0 = bias1v[0], a1m1 = bias1v[1];

        // x-part of layer0 overlaps staging latency
        if (t < TT){
            const float* xp = x + ((size_t)(gbase+lr)*TT + t)*II + lk*8;
            half8 bx0 = cvt8v(xp);
            half8 bx1 = cvt8v(xp + 32);
            a0m0 = MFMA(wA0[8][0], bx0, a0m0);
            a0m1 = MFMA(wA0[8][1], bx0, a0m1);
            a0m0 = MFMA(wA0[9][0], bx1, a0m0);
            a0m1 = MFMA(wA0[9][1], bx1, a0m1);
        }
        __syncthreads();   // staging visible to all waves

        if (t > 0){
            const char* sb = (const char*)&stg[t&1][0][0][0];
            half8 bh0[8];
#pragma unroll
            for (int kt=0;kt<8;++kt)
                bh0[kt] = *(const half8*)(sb + kt*1280 + lr*80 + lk*16);
            if (t < TT){
#pragma unroll
                for (int kt=0;kt<8;++kt){
                    a0m0 = MFMA(wA0[kt][0], bh0[kt], a0m0);
                    a0m1 = MFMA(wA0[kt][1], bh0[kt], a0m1);
                }
            }
#pragma unroll
            for (int kt=0;kt<8;++kt){       // Wih1 * h0(t-1)
                a1m0 = MFMA(wA1[8+kt][0], bh0[kt], a1m0);
                a1m1 = MFMA(wA1[8+kt][1], bh0[kt], a1m1);
            }
            if (t >= 2){
#pragma unroll
                for (int kt=0;kt<8;++kt){   // Whh1 * h1(t-2)
                    half8 bh1 = *(const half8*)(sb + (8+kt)*1280 + lr*80 + lk*16);
                    a1m0 = MFMA(wA1[kt][0], bh1, a1m0);
                    a1m1 = MFMA(wA1[kt][1], bh1, a1m1);
                }
            }
        }

        // ---- activations + cache-bypass h stores ----
        if (t < TT){
            unsigned short* D0 = (unsigned short*)(hb0 + ((size_t)((t&1)*NG + g)*16)*HH);
            {
                float ig=sigm(a0m0[0]), fg=sigm(a0m0[1]), gg=tanhf_(a0m0[2]), og=sigm(a0m0[3]);
                c0s0 = fg*c0s0 + ig*gg;
                ASTORE16(&D0[lr*HH + cD0], h2u(og*tanhf_(c0s0)));
            }
            {
                float ig=sigm(a0m1[0]), fg=sigm(a0m1[1]), gg=tanhf_(a0m1[2]), og=sigm(a0m1[3]);
                c0s1 = fg*c0s1 + ig*gg;
                ASTORE16(&D0[lr*HH + cD0 + 4], h2u(og*tanhf_(c0s1)));
            }
        }
        if (t > 0){
            unsigned short* D1 = (unsigned short*)(hb1 + ((size_t)(((t-1)&1)*NG + g)*16)*HH);
            {
                float ig=sigm(a1m0[0]), fg=sigm(a1m0[1]), gg=tanhf_(a1m0[2]), og=sigm(a1m0[3]);
                c1s0 = fg*c1s0 + ig*gg;
                ASTORE16(&D1[lr*HH + cD0], h2u(og*tanhf_(c1s0)));
            }
            {
                float ig=sigm(a1m1[0]), fg=sigm(a1m1[1]), gg=tanhf_(a1m1[2]), og=sigm(a1m1[3]);
                c1s1 = fg*c1s1 + ig*gg;
                ASTORE16(&D1[lr*HH + cD0 + 4], h2u(og*tanhf_(c1s1)));
            }
        }

        // ---- per-wave release (stores done) + flag inc + poll to 32 ----
        asm volatile("s_waitcnt vmcnt(0)" ::: "memory");
        if (l == 0){
            unsigned* fp = fgrp + t;
            __hip_atomic_fetch_add(fp, 1u, __ATOMIC_RELAXED, __HIP_MEMORY_SCOPE_AGENT);
            while (__hip_atomic_load(fp, __ATOMIC_RELAXED, __HIP_MEMORY_SCOPE_AGENT) < WPG) {}
        }
        asm volatile("" ::: "memory");
    }

    // ---- epilogue: slice 0 of each group; reuse stg LDS as f32 scratch ----
    if (s == 0){
        float* hl  = (float*)&stg[0][0][0][0];   // [16][256]
        float* zsh = hl + 16*256;                // [16][128]
        const unsigned long long* HL = (const unsigned long long*)hb1
            + ((size_t)(((TT-1)&1)*NG + g)*16)*64;
        for (int i = tid; i < 1024; i += 256){
            const int r = i >> 6, q = i & 63;
            unsigned long long v = ALOAD64(HL + (size_t)r*64 + q);
            union { unsigned long long u; _Float16 h[4]; } cv; cv.u = v;
#pragma unroll
            for (int e=0;e<4;++e) hl[r*256 + q*4 + e] = (float)cv.h[e];
        }
        __syncthreads();
        for (int idx = tid; idx < 2048; idx += 256){
            const int r = idx >> 7, j = idx & 127;
            const float* wrow = W1 + j*HH;
            const float* hr = hl + r*256;
            float ssum = b1[j];
            for (int k=0;k<HH;k+=4){
                f32x4v wv = *(const f32x4v*)(wrow + k);
                ssum += hr[k]*wv[0] + hr[k+1]*wv[1] + hr[k+2]*wv[2] + hr[k+3]*wv[3];
            }
            zsh[r*128 + j] = tanhf_(ssum);
        }
        __syncthreads();
        for (int idx = tid; idx < 1536; idx += 256){
            const int r = idx / 96, o = idx - r*96;
            const float* wrow = W2 + o*128;
            const float* zr = zsh + r*128;
            float ssum = b2[o];
            for (int k=0;k<128;k+=4){
                f32x4v wv = *(const f32x4v*)(wrow + k);
                ssum += zr[k]*wv[0] + zr[k+1]*wv[1] + zr[k+2]*wv[2] + zr[k+3]*wv[3];
            }
            out[(size_t)(gbase+r)*96 + o] = ssum;
        }
    }
}

extern "C" void kernel_launch(void* const* d_in, const int* in_sizes, int n_in,
                              void* d_out, int out_size, void* d_ws, size_t ws_size,
                              hipStream_t stream) {
    const float* x    = (const float*)d_in[0];
    const float* Wih0 = (const float*)d_in[1];
    const float* Whh0 = (const float*)d_in[2];
    const float* bih0 = (const float*)d_in[3];
    const float* bhh0 = (const float*)d_in[4];
    const float* Wih1 = (const float*)d_in[5];
    const float* Whh1 = (const float*)d_in[6];
    const float* bih1 = (const float*)d_in[7];
    const float* bhh1 = (const float*)d_in[8];
    const float* W1   = (const float*)d_in[9];
    const float* b1   = (const float*)d_in[10];
    const float* W2   = (const float*)d_in[11];
    const float* b2   = (const float*)d_in[12];

    // workspace: flags (64 KB, zeroed per call) | hb0 (256 KB) | hb1 (256 KB)
    unsigned*  flags = (unsigned*)d_ws;
    _Float16*  hb0   = (_Float16*)((char*)d_ws + 65536);
    _Float16*  hb1   = hb0 + 2*NG*16*HH;

    hipMemsetAsync(d_ws, 0, 65536, stream);

    hipLaunchKernelGGL(lstm_pers, dim3(NG*NS), dim3(256), 0, stream,
                       x, Wih0, Whh0, bih0, bhh0,
                       Wih1, Whh1, bih1, bhh1,
                       W1, b1, W2, b2,
                       flags, hb0, hb1, (float*)d_out);
}

// Round 4
// 3054.077 us; speedup vs baseline: 7.2624x; 1.2257x over previous
//
#include <hip/hip_runtime.h>

#define TT 512
#define II 64
#define HH 256
#define NG 16          // batch groups (16 rows each)
#define NS 8           // gate slices per group (32 channels each)
#define WPG 32u        // waves per group = NS * 4
#define FST 544        // flag stride per group (>= TT+1)

typedef _Float16 half8 __attribute__((ext_vector_type(8)));
typedef float f32x4 __attribute__((ext_vector_type(4)));
typedef float f32x4v __attribute__((ext_vector_type(4)));

__device__ __forceinline__ float sigm(float x){ return 1.0f/(1.0f+__expf(-x)); }
__device__ __forceinline__ float tanhf_(float x){ float e=__expf(2.0f*x); return 1.0f-2.0f/(e+1.0f); }

union HU { _Float16 h; unsigned short u; };
__device__ __forceinline__ unsigned short h2u(float f){ HU x; x.h=(_Float16)f; return x.u; }

__device__ __forceinline__ half8 cvt8v(const float* __restrict__ p){
    f32x4v a = *(const f32x4v*)p, b = *(const f32x4v*)(p+4);
    half8 r;
    r[0]=(_Float16)a[0]; r[1]=(_Float16)a[1]; r[2]=(_Float16)a[2]; r[3]=(_Float16)a[3];
    r[4]=(_Float16)b[0]; r[5]=(_Float16)b[1]; r[6]=(_Float16)b[2]; r[7]=(_Float16)b[3];
    return r;
}

// Pin a weight fragment into the AGPR file. Opaque asm result cannot be
// rematerialized (kills the reload+reconvert the allocator did in r3), and
// AGPRs are otherwise idle so no spill pressure. MFMA reads A from AGPR.
__device__ __forceinline__ void pina(half8& v){ asm volatile("" : "+a"(v)); }
__device__ __forceinline__ void pinv(f32x4& v){ asm volatile("" : "+v"(v)); }

#define MFMA(A,B,C) __builtin_amdgcn_mfma_f32_16x16x32_f16((A),(B),(C),0,0,0)
#define ALOAD64(p)   __hip_atomic_load((p), __ATOMIC_RELAXED, __HIP_MEMORY_SCOPE_AGENT)
#define ASTORE64(p,v) __hip_atomic_store((p), (v), __ATOMIC_RELAXED, __HIP_MEMORY_SCOPE_AGENT)

// Persistent gate-sliced, layer-pipelined 2-layer LSTM.
// 128 WGs x 256 thr: group=blockIdx%16 (16 batch rows), slice=blockIdx/16 (32 chans).
// Superstep t: compute h0(t) [t<TT] and h1(t-1) [t>0] -> ONE flag per superstep.
// Cross-WG data via relaxed agent-scope atomics (no fences, no L2 wb/inv).
__global__ __launch_bounds__(256,1) __attribute__((amdgpu_waves_per_eu(1)))
void lstm_pers(
    const float* __restrict__ x,
    const float* __restrict__ Wih0, const float* __restrict__ Whh0,
    const float* __restrict__ bih0, const float* __restrict__ bhh0,
    const float* __restrict__ Wih1, const float* __restrict__ Whh1,
    const float* __restrict__ bih1, const float* __restrict__ bhh1,
    const float* __restrict__ W1, const float* __restrict__ b1,
    const float* __restrict__ W2, const float* __restrict__ b2,
    unsigned* __restrict__ flags,
    _Float16* __restrict__ hb0, _Float16* __restrict__ hb1,
    float* __restrict__ out)
{
    // staging: [buf2][tile16][row16][40 halves]; row stride 80B (2-way alias = free)
    __shared__ __align__(16) _Float16 stg[2][16][16][40];        // 40 KB
    // per-wave store-transpose tiles: [layer][wave][row16][chan8] u16
    __shared__ __align__(16) unsigned short twv[2][4][16][8];    // 2 KB

    const int tid = threadIdx.x;
    const int w   = tid >> 6;
    const int l   = tid & 63;
    const int lr  = l & 15;
    const int lk  = l >> 4;
    const int g   = blockIdx.x & (NG-1);
    const int s   = blockIdx.x >> 4;
    const int gbase = g * 16;
    const int cw  = s*32 + w*8;

    // ---- resident weight fragments (MFMA A-operand), pinned into AGPRs ----
    half8 wA0[10][2];   // layer0: kt<8 -> Whh0 (K=256), kt=8,9 -> Wih0 (K=64)
    half8 wA1[16][2];   // layer1: kt<8 -> Whh1, kt>=8 -> Wih1
    f32x4 bias0v[2], bias1v[2];
#pragma unroll
    for (int m=0;m<2;++m){
        const int n = (lr&3)*HH + cw + m*4 + (lr>>2);
#pragma unroll
        for (int kt=0;kt<10;++kt){
            const float* src = (kt<8) ? (Whh0 + (size_t)n*HH + kt*32 + lk*8)
                                      : (Wih0 + (size_t)n*II + (kt-8)*32 + lk*8);
            wA0[kt][m] = cvt8v(src);
            pina(wA0[kt][m]);
        }
#pragma unroll
        for (int kt=0;kt<16;++kt){
            const float* src = (kt<8) ? (Whh1 + (size_t)n*HH + kt*32 + lk*8)
                                      : (Wih1 + (size_t)n*HH + (kt-8)*32 + lk*8);
            wA1[kt][m] = cvt8v(src);
            pina(wA1[kt][m]);
        }
        const int cD = cw + m*4 + lk;
#pragma unroll
        for (int j=0;j<4;++j){
            bias0v[m][j] = bih0[j*HH+cD] + bhh0[j*HH+cD];
            bias1v[m][j] = bih1[j*HH+cD] + bhh1[j*HH+cD];
        }
        pinv(bias0v[m]); pinv(bias1v[m]);
    }

    float c0s0=0.f, c0s1=0.f, c1s0=0.f, c1s1=0.f;
    unsigned* fgrp = flags + g*FST;

    for (int t=0; t<=TT; ++t){
        // ---- cooperative staging: tiles 0..7 = h0(t-1), 8..15 = h1(t-2) ----
        if (t > 0){
            const int ntile = (t >= 2) ? 16 : 8;
            char* sb = (char*)&stg[t&1][0][0][0];
            const unsigned long long* H0 = (const unsigned long long*)hb0
                + ((size_t)(((t-1)&1)*NG + g)*16)*64;
            const unsigned long long* H1 = (const unsigned long long*)hb1
                + ((size_t)((t&1)*NG + g)*16)*64;
#pragma unroll
            for (int i=0;i<8;++i){
                const int uidx = i*256 + tid;
                const int tile = uidx >> 7;
                if (tile < ntile){
                    const int u = uidx & 127, r = u >> 3, q = u & 7;
                    const unsigned long long* srcp = (tile < 8)
                        ? (H0 + (size_t)r*64 + tile*8 + q)
                        : (H1 + (size_t)r*64 + (tile-8)*8 + q);
                    unsigned long long v = ALOAD64(srcp);
                    *(unsigned long long*)(sb + tile*1280 + r*80 + q*8) = v;
                }
            }
        }

        f32x4 a0m0 = bias0v[0], a0m1 = bias0v[1];
        f32x4 a1m0 = bias1v[0], a1m1 = bias1v[1];

        // x-part of layer0 overlaps staging latency
        if (t < TT){
            const float* xp = x + ((size_t)(gbase+lr)*TT + t)*II + lk*8;
            half8 bx0 = cvt8v(xp);
            half8 bx1 = cvt8v(xp + 32);
            a0m0 = MFMA(wA0[8][0], bx0, a0m0);
            a0m1 = MFMA(wA0[8][1], bx0, a0m1);
            a0m0 = MFMA(wA0[9][0], bx1, a0m0);
            a0m1 = MFMA(wA0[9][1], bx1, a0m1);
        }
        __syncthreads();   // staging visible to all waves

        if (t > 0){
            const char* sb = (const char*)&stg[t&1][0][0][0];
            half8 bh0[8];
#pragma unroll
            for (int kt=0;kt<8;++kt)
                bh0[kt] = *(const half8*)(sb + kt*1280 + lr*80 + lk*16);
            if (t < TT){
#pragma unroll
                for (int kt=0;kt<8;++kt){
                    a0m0 = MFMA(wA0[kt][0], bh0[kt], a0m0);
                    a0m1 = MFMA(wA0[kt][1], bh0[kt], a0m1);
                }
            }
#pragma unroll
            for (int kt=0;kt<8;++kt){       // Wih1 * h0(t-1)
                a1m0 = MFMA(wA1[8+kt][0], bh0[kt], a1m0);
                a1m1 = MFMA(wA1[8+kt][1], bh0[kt], a1m1);
            }
            if (t >= 2){
#pragma unroll
                for (int kt=0;kt<8;++kt){   // Whh1 * h1(t-2)
                    half8 bh1 = *(const half8*)(sb + (8+kt)*1280 + lr*80 + lk*16);
                    a1m0 = MFMA(wA1[kt][0], bh1, a1m0);
                    a1m1 = MFMA(wA1[kt][1], bh1, a1m1);
                }
            }
        }

        // ---- activations -> per-wave LDS transpose tile ----
        if (t < TT){
            float ig=sigm(a0m0[0]), fg=sigm(a0m0[1]), gg=tanhf_(a0m0[2]), og=sigm(a0m0[3]);
            c0s0 = fg*c0s0 + ig*gg;
            twv[0][w][lr][lk]   = h2u(og*tanhf_(c0s0));
            float ig1=sigm(a0m1[0]), fg1=sigm(a0m1[1]), gg1=tanhf_(a0m1[2]), og1=sigm(a0m1[3]);
            c0s1 = fg1*c0s1 + ig1*gg1;
            twv[0][w][lr][lk+4] = h2u(og1*tanhf_(c0s1));
        }
        if (t > 0){
            float ig=sigm(a1m0[0]), fg=sigm(a1m0[1]), gg=tanhf_(a1m0[2]), og=sigm(a1m0[3]);
            c1s0 = fg*c1s0 + ig*gg;
            twv[1][w][lr][lk]   = h2u(og*tanhf_(c1s0));
            float ig1=sigm(a1m1[0]), fg1=sigm(a1m1[1]), gg1=tanhf_(a1m1[2]), og1=sigm(a1m1[3]);
            c1s1 = fg1*c1s1 + ig1*gg1;
            twv[1][w][lr][lk+4] = h2u(og1*tanhf_(c1s1));
        }
        asm volatile("s_waitcnt lgkmcnt(0)" ::: "memory");

        // ---- coalesced u64 agent stores: lanes 0..31, one u64 each ----
        if (l < 32){
            const int r = l >> 1, hh = l & 1;
            if (t < TT){
                unsigned long long v = *(const unsigned long long*)&twv[0][w][r][hh*4];
                unsigned long long* D0 = (unsigned long long*)hb0
                    + ((size_t)((t&1)*NG + g)*16)*64 + (size_t)r*64 + (cw>>2) + hh;
                ASTORE64(D0, v);
            }
            if (t > 0){
                unsigned long long v = *(const unsigned long long*)&twv[1][w][r][hh*4];
                unsigned long long* D1 = (unsigned long long*)hb1
                    + ((size_t)(((t-1)&1)*NG + g)*16)*64 + (size_t)r*64 + (cw>>2) + hh;
                ASTORE64(D1, v);
            }
        }

        // ---- per-wave release (stores drained) + flag inc; wave0 polls ----
        asm volatile("s_waitcnt vmcnt(0)" ::: "memory");
        if (l == 0){
            __hip_atomic_fetch_add(fgrp + t, 1u, __ATOMIC_RELAXED, __HIP_MEMORY_SCOPE_AGENT);
            if (w == 0)
                while (__hip_atomic_load(fgrp + t, __ATOMIC_RELAXED, __HIP_MEMORY_SCOPE_AGENT) < WPG) {}
        }
        __syncthreads();   // wave0's poll releases waves 1..3
    }

    // ---- epilogue: slice 0 of each group; reuse stg LDS as f32 scratch ----
    if (s == 0){
        float* hl  = (float*)&stg[0][0][0][0];   // [16][256]
        float* zsh = hl + 16*256;                // [16][128]
        const unsigned long long* HL = (const unsigned long long*)hb1
            + ((size_t)(((TT-1)&1)*NG + g)*16)*64;
        for (int i = tid; i < 1024; i += 256){
            const int r = i >> 6, q = i & 63;
            unsigned long long v = ALOAD64(HL + (size_t)r*64 + q);
            union { unsigned long long u; _Float16 h[4]; } cv; cv.u = v;
#pragma unroll
            for (int e=0;e<4;++e) hl[r*256 + q*4 + e] = (float)cv.h[e];
        }
        __syncthreads();
        for (int idx = tid; idx < 2048; idx += 256){
            const int r = idx >> 7, j = idx & 127;
            const float* wrow = W1 + j*HH;
            const float* hr = hl + r*256;
            float ssum = b1[j];
            for (int k=0;k<HH;k+=4){
                f32x4v wv = *(const f32x4v*)(wrow + k);
                ssum += hr[k]*wv[0] + hr[k+1]*wv[1] + hr[k+2]*wv[2] + hr[k+3]*wv[3];
            }
            zsh[r*128 + j] = tanhf_(ssum);
        }
        __syncthreads();
        for (int idx = tid; idx < 1536; idx += 256){
            const int r = idx / 96, o = idx - r*96;
            const float* wrow = W2 + o*128;
            const float* zr = zsh + r*128;
            float ssum = b2[o];
            for (int k=0;k<128;k+=4){
                f32x4v wv = *(const f32x4v*)(wrow + k);
                ssum += zr[k]*wv[0] + zr[k+1]*wv[1] + zr[k+2]*wv[2] + zr[k+3]*wv[3];
            }
            out[(size_t)(gbase+r)*96 + o] = ssum;
        }
    }
}

extern "C" void kernel_launch(void* const* d_in, const int* in_sizes, int n_in,
                              void* d_out, int out_size, void* d_ws, size_t ws_size,
                              hipStream_t stream) {
    const float* x    = (const float*)d_in[0];
    const float* Wih0 = (const float*)d_in[1];
    const float* Whh0 = (const float*)d_in[2];
    const float* bih0 = (const float*)d_in[3];
    const float* bhh0 = (const float*)d_in[4];
    const float* Wih1 = (const float*)d_in[5];
    const float* Whh1 = (const float*)d_in[6];
    const float* bih1 = (const float*)d_in[7];
    const float* bhh1 = (const float*)d_in[8];
    const float* W1   = (const float*)d_in[9];
    const float* b1   = (const float*)d_in[10];
    const float* W2   = (const float*)d_in[11];
    const float* b2   = (const float*)d_in[12];

    // workspace: flags (64 KB, zeroed per call) | hb0 (256 KB) | hb1 (256 KB)
    unsigned*  flags = (unsigned*)d_ws;
    _Float16*  hb0   = (_Float16*)((char*)d_ws + 65536);
    _Float16*  hb1   = hb0 + 2*NG*16*HH;

    hipMemsetAsync(d_ws, 0, 65536, stream);

    hipLaunchKernelGGL(lstm_pers, dim3(NG*NS), dim3(256), 0, stream,
                       x, Wih0, Whh0, bih0, bhh0,
                       Wih1, Whh1, bih1, bhh1,
                       W1, b1, W2, b2,
                       flags, hb0, hb1, (float*)d_out);
}

// Round 5
// 2837.832 us; speedup vs baseline: 7.8158x; 1.0762x over previous
//
#include <hip/hip_runtime.h>

#define TT 512
#define II 64
#define HH 256
#define NG 16          // batch groups (16 rows each)
#define NS 8           // gate slices per group (32 channels each)
#define FST 520        // flag t-slots per group (>= TT+1)

typedef _Float16 half8 __attribute__((ext_vector_type(8)));
typedef float f32x4 __attribute__((ext_vector_type(4)));
typedef float f32x4v __attribute__((ext_vector_type(4)));

__device__ __forceinline__ float sigm(float x){ return 1.0f/(1.0f+__expf(-x)); }
__device__ __forceinline__ float tanhf_(float x){ float e=__expf(2.0f*x); return 1.0f-2.0f/(e+1.0f); }

union HU { _Float16 h; unsigned short u; };
__device__ __forceinline__ unsigned short h2u(float f){ HU x; x.h=(_Float16)f; return x.u; }

__device__ __forceinline__ half8 cvt8v(const float* __restrict__ p){
    f32x4v a = *(const f32x4v*)p, b = *(const f32x4v*)(p+4);
    half8 r;
    r[0]=(_Float16)a[0]; r[1]=(_Float16)a[1]; r[2]=(_Float16)a[2]; r[3]=(_Float16)a[3];
    r[4]=(_Float16)b[0]; r[5]=(_Float16)b[1]; r[6]=(_Float16)b[2]; r[7]=(_Float16)b[3];
    return r;
}

// Pin weight fragments into the AGPR file (opaque asm result cannot be
// rematerialized; AGPRs otherwise idle; MFMA reads A from AGPR directly).
__device__ __forceinline__ void pina(half8& v){ asm volatile("" : "+a"(v)); }
__device__ __forceinline__ void pinv(f32x4& v){ asm volatile("" : "+v"(v)); }

#define MFMA(A,B,C) __builtin_amdgcn_mfma_f32_16x16x32_f16((A),(B),(C),0,0,0)
#define ALOAD64(p)    __hip_atomic_load((p), __ATOMIC_RELAXED, __HIP_MEMORY_SCOPE_AGENT)
#define ASTORE64(p,v) __hip_atomic_store((p), (v), __ATOMIC_RELAXED, __HIP_MEMORY_SCOPE_AGENT)
#define ASTORE16(p,v) __hip_atomic_store((p), (v), __ATOMIC_RELAXED, __HIP_MEMORY_SCOPE_AGENT)

// Persistent gate-sliced, layer-pipelined 2-layer LSTM.
// 128 WGs x 256 thr: group=blockIdx%16 (16 batch rows), slice=blockIdx/16 (32 chans).
// Superstep t: compute h0(t) [t<TT] and h1(t-1) [t>0].
// Sync: per (group,t) 8 u16 slots (one per slice WG) -- independent stores,
// no RMW serialization; poller compares 2xu64 against replicated pattern.
// h layout: blocked [buf][g][chanblock8][row16][chan8] -> each wave stores one
// contiguous 256B tile (lanes 0..31 x u64).
__global__ __launch_bounds__(256,1) __attribute__((amdgpu_waves_per_eu(1)))
void lstm_pers(
    const float* __restrict__ x,
    const float* __restrict__ Wih0, const float* __restrict__ Whh0,
    const float* __restrict__ bih0, const float* __restrict__ bhh0,
    const float* __restrict__ Wih1, const float* __restrict__ Whh1,
    const float* __restrict__ bih1, const float* __restrict__ bhh1,
    const float* __restrict__ W1, const float* __restrict__ b1,
    const float* __restrict__ W2, const float* __restrict__ b2,
    unsigned short* __restrict__ flags,
    _Float16* __restrict__ hb0, _Float16* __restrict__ hb1,
    float* __restrict__ out)
{
    // staging: [buf2][tile16][row16][40 halves]; row stride 80B
    __shared__ __align__(16) _Float16 stg[2][16][16][40];        // 40 KB
    // per-wave store-transpose tiles: [layer][wave][row16][chan8] u16
    __shared__ __align__(16) unsigned short twv[2][4][16][8];    // 2 KB

    const int tid = threadIdx.x;
    const int w   = tid >> 6;
    const int l   = tid & 63;
    const int lr  = l & 15;
    const int lk  = l >> 4;
    const int g   = blockIdx.x & (NG-1);
    const int s   = blockIdx.x >> 4;
    const int gbase = g * 16;
    const int cw  = s*32 + w*8;

    // ---- resident weight fragments (MFMA A-operand), pinned into AGPRs ----
    half8 wA0[10][2];   // layer0: kt<8 -> Whh0 (K=256), kt=8,9 -> Wih0 (K=64)
    half8 wA1[16][2];   // layer1: kt<8 -> Whh1, kt>=8 -> Wih1
    f32x4 bias0v[2], bias1v[2];
#pragma unroll
    for (int m=0;m<2;++m){
        const int n = (lr&3)*HH + cw + m*4 + (lr>>2);
#pragma unroll
        for (int kt=0;kt<10;++kt){
            const float* src = (kt<8) ? (Whh0 + (size_t)n*HH + kt*32 + lk*8)
                                      : (Wih0 + (size_t)n*II + (kt-8)*32 + lk*8);
            wA0[kt][m] = cvt8v(src);
            pina(wA0[kt][m]);
        }
#pragma unroll
        for (int kt=0;kt<16;++kt){
            const float* src = (kt<8) ? (Whh1 + (size_t)n*HH + kt*32 + lk*8)
                                      : (Wih1 + (size_t)n*HH + (kt-8)*32 + lk*8);
            wA1[kt][m] = cvt8v(src);
            pina(wA1[kt][m]);
        }
        const int cD = cw + m*4 + lk;
#pragma unroll
        for (int j=0;j<4;++j){
            bias0v[m][j] = bih0[j*HH+cD] + bhh0[j*HH+cD];
            bias1v[m][j] = bih1[j*HH+cD] + bhh1[j*HH+cD];
        }
        pinv(bias0v[m]); pinv(bias1v[m]);
    }

    float c0s0=0.f, c0s1=0.f, c1s0=0.f, c1s1=0.f;
    unsigned short* fgrp = flags + (size_t)g*FST*8;
    const int cb = s*4 + w;   // this wave's channel block (0..31)

    for (int t=0; t<=TT; ++t){
        // ---- cooperative staging: tiles 0..7 = h0(t-1), 8..15 = h1(t-2) ----
        if (t > 0){
            const int ntile = (t >= 2) ? 16 : 8;
            char* sb = (char*)&stg[t&1][0][0][0];
            const unsigned long long* H0 = (const unsigned long long*)hb0
                + ((size_t)(((t-1)&1)*NG + g))*1024;
            const unsigned long long* H1 = (const unsigned long long*)hb1
                + ((size_t)((t&1)*NG + g))*1024;
#pragma unroll
            for (int i=0;i<8;++i){
                const int uidx = i*256 + tid;
                const int tile = uidx >> 7;
                if (tile < ntile){
                    const int u = uidx & 127, r = u >> 3, q = u & 7;
                    // blocked source: block = (tile&7)*4 + (q>>1), elem = r*2 + (q&1)
                    const size_t gi = (size_t)((tile&7)*4 + (q>>1))*32 + r*2 + (q&1);
                    unsigned long long v = (tile < 8) ? ALOAD64(H0 + gi) : ALOAD64(H1 + gi);
                    *(unsigned long long*)(sb + tile*1280 + r*80 + q*8) = v;
                }
            }
        }

        f32x4 a0m0 = bias0v[0], a0m1 = bias0v[1];
        f32x4 a1m0 = bias1v[0], a1m1 = bias1v[1];

        // x-part of layer0 overlaps staging latency
        if (t < TT){
            const float* xp = x + ((size_t)(gbase+lr)*TT + t)*II + lk*8;
            half8 bx0 = cvt8v(xp);
            half8 bx1 = cvt8v(xp + 32);
            a0m0 = MFMA(wA0[8][0], bx0, a0m0);
            a0m1 = MFMA(wA0[8][1], bx0, a0m1);
            a0m0 = MFMA(wA0[9][0], bx1, a0m0);
            a0m1 = MFMA(wA0[9][1], bx1, a0m1);
        }
        __syncthreads();   // staging visible to all waves

        if (t > 0){
            const char* sb = (const char*)&stg[t&1][0][0][0];
            half8 bh0[8];
#pragma unroll
            for (int kt=0;kt<8;++kt)
                bh0[kt] = *(const half8*)(sb + kt*1280 + lr*80 + lk*16);
            if (t < TT){
#pragma unroll
                for (int kt=0;kt<8;++kt){
                    a0m0 = MFMA(wA0[kt][0], bh0[kt], a0m0);
                    a0m1 = MFMA(wA0[kt][1], bh0[kt], a0m1);
                }
            }
#pragma unroll
            for (int kt=0;kt<8;++kt){       // Wih1 * h0(t-1)
                a1m0 = MFMA(wA1[8+kt][0], bh0[kt], a1m0);
                a1m1 = MFMA(wA1[8+kt][1], bh0[kt], a1m1);
            }
            if (t >= 2){
#pragma unroll
                for (int kt=0;kt<8;++kt){   // Whh1 * h1(t-2)
                    half8 bh1 = *(const half8*)(sb + (8+kt)*1280 + lr*80 + lk*16);
                    a1m0 = MFMA(wA1[kt][0], bh1, a1m0);
                    a1m1 = MFMA(wA1[kt][1], bh1, a1m1);
                }
            }
        }

        // ---- activations -> per-wave LDS transpose tile ----
        if (t < TT){
            float ig=sigm(a0m0[0]), fg=sigm(a0m0[1]), gg=tanhf_(a0m0[2]), og=sigm(a0m0[3]);
            c0s0 = fg*c0s0 + ig*gg;
            twv[0][w][lr][lk]   = h2u(og*tanhf_(c0s0));
            float ig1=sigm(a0m1[0]), fg1=sigm(a0m1[1]), gg1=tanhf_(a0m1[2]), og1=sigm(a0m1[3]);
            c0s1 = fg1*c0s1 + ig1*gg1;
            twv[0][w][lr][lk+4] = h2u(og1*tanhf_(c0s1));
        }
        if (t > 0){
            float ig=sigm(a1m0[0]), fg=sigm(a1m0[1]), gg=tanhf_(a1m0[2]), og=sigm(a1m0[3]);
            c1s0 = fg*c1s0 + ig*gg;
            twv[1][w][lr][lk]   = h2u(og*tanhf_(c1s0));
            float ig1=sigm(a1m1[0]), fg1=sigm(a1m1[1]), gg1=tanhf_(a1m1[2]), og1=sigm(a1m1[3]);
            c1s1 = fg1*c1s1 + ig1*gg1;
            twv[1][w][lr][lk+4] = h2u(og1*tanhf_(c1s1));
        }
        asm volatile("s_waitcnt lgkmcnt(0)" ::: "memory");

        // ---- coalesced blocked stores: lanes 0..31, one u64 each, 256B/wave ----
        if (l < 32){
            if (t < TT){
                unsigned long long v = *(const unsigned long long*)&twv[0][w][l>>1][(l&1)*4];
                unsigned long long* D0 = (unsigned long long*)hb0
                    + ((size_t)((t&1)*NG + g))*1024 + cb*32 + l;
                ASTORE64(D0, v);
            }
            if (t > 0){
                unsigned long long v = *(const unsigned long long*)&twv[1][w][l>>1][(l&1)*4];
                unsigned long long* D1 = (unsigned long long*)hb1
                    + ((size_t)(((t-1)&1)*NG + g))*1024 + cb*32 + l;
                ASTORE64(D1, v);
            }
        }

        // ---- signal: drain stores per wave, barrier, one u16 slot store/WG ----
        asm volatile("s_waitcnt vmcnt(0)" ::: "memory");
        __syncthreads();   // all 4 waves' stores globally visible
        if (tid == 0){
            ASTORE16(&fgrp[t*8 + s], (unsigned short)(t+1));
            const unsigned long long pat =
                0x0001000100010001ULL * (unsigned long long)(t+1);
            const unsigned long long* fp = (const unsigned long long*)(fgrp + t*8);
            for (;;){
                unsigned long long a = ALOAD64(fp);
                unsigned long long b = ALOAD64(fp+1);
                if (a == pat && b == pat) break;
            }
        }
        __syncthreads();   // tid0's detect releases the WG
    }

    // ---- epilogue: slice 0 of each group; reuse stg LDS as f32 scratch ----
    if (s == 0){
        float* hl  = (float*)&stg[0][0][0][0];   // [16][256]
        float* zsh = hl + 16*256;                // [16][128]
        const unsigned long long* HL = (const unsigned long long*)hb1
            + ((size_t)(((TT-1)&1)*NG + g))*1024;
        for (int i = tid; i < 1024; i += 256){
            const int r = i >> 6, q = i & 63;
            const size_t gi = (size_t)(q>>1)*32 + r*2 + (q&1);
            unsigned long long v = ALOAD64(HL + gi);
            union { unsigned long long u; _Float16 h[4]; } cv; cv.u = v;
#pragma unroll
            for (int e=0;e<4;++e) hl[r*256 + q*4 + e] = (float)cv.h[e];
        }
        __syncthreads();
        for (int idx = tid; idx < 2048; idx += 256){
            const int r = idx >> 7, j = idx & 127;
            const float* wrow = W1 + j*HH;
            const float* hr = hl + r*256;
            float ssum = b1[j];
            for (int k=0;k<HH;k+=4){
                f32x4v wv = *(const f32x4v*)(wrow + k);
                ssum += hr[k]*wv[0] + hr[k+1]*wv[1] + hr[k+2]*wv[2] + hr[k+3]*wv[3];
            }
            zsh[r*128 + j] = tanhf_(ssum);
        }
        __syncthreads();
        for (int idx = tid; idx < 1536; idx += 256){
            const int r = idx / 96, o = idx - r*96;
            const float* wrow = W2 + o*128;
            const float* zr = zsh + r*128;
            float ssum = b2[o];
            for (int k=0;k<128;k+=4){
                f32x4v wv = *(const f32x4v*)(wrow + k);
                ssum += zr[k]*wv[0] + zr[k+1]*wv[1] + zr[k+2]*wv[2] + zr[k+3]*wv[3];
            }
            out[(size_t)(gbase+r)*96 + o] = ssum;
        }
    }
}

extern "C" void kernel_launch(void* const* d_in, const int* in_sizes, int n_in,
                              void* d_out, int out_size, void* d_ws, size_t ws_size,
                              hipStream_t stream) {
    const float* x    = (const float*)d_in[0];
    const float* Wih0 = (const float*)d_in[1];
    const float* Whh0 = (const float*)d_in[2];
    const float* bih0 = (const float*)d_in[3];
    const float* bhh0 = (const float*)d_in[4];
    const float* Wih1 = (const float*)d_in[5];
    const float* Whh1 = (const float*)d_in[6];
    const float* bih1 = (const float*)d_in[7];
    const float* bhh1 = (const float*)d_in[8];
    const float* W1   = (const float*)d_in[9];
    const float* b1   = (const float*)d_in[10];
    const float* W2   = (const float*)d_in[11];
    const float* b2   = (const float*)d_in[12];

    // workspace: flags 16*520*8 u16 = 133,120 B (zeroed per call)
    //            hb0/hb1 blocked: 2 bufs * 16 g * 32 blk * 256 B = 262,144 B each
    unsigned short* flags = (unsigned short*)d_ws;
    _Float16* hb0 = (_Float16*)((char*)d_ws + 139264);
    _Float16* hb1 = (_Float16*)((char*)d_ws + 139264 + 262144);

    hipMemsetAsync(d_ws, 0, NG*FST*8*sizeof(unsigned short), stream);

    hipLaunchKernelGGL(lstm_pers, dim3(NG*NS), dim3(256), 0, stream,
                       x, Wih0, Whh0, bih0, bhh0,
                       Wih1, Whh1, bih1, bhh1,
                       W1, b1, W2, b2,
                       flags, hb0, hb1, (float*)d_out);
}

// Round 7
// 2363.362 us; speedup vs baseline: 9.3849x; 1.2008x over previous
//
#include <hip/hip_runtime.h>

#define TT 512
#define II 64
#define HH 256
#define NG 16          // batch groups (16 rows each)
#define NS 8           // gate slices per group (32 channels each)
#define FST 520        // flag lines per group (>= TT+1), 32 u16 (64B) each

typedef _Float16 half8 __attribute__((ext_vector_type(8)));
typedef float f32x4 __attribute__((ext_vector_type(4)));

__device__ __forceinline__ float sigm(float x){ return 1.0f/(1.0f+__expf(-x)); }
__device__ __forceinline__ float tanhf_(float x){ float e=__expf(2.0f*x); return 1.0f-2.0f/(e+1.0f); }

union HU { _Float16 h; unsigned short u; };
__device__ __forceinline__ unsigned short h2u(float f){ HU x; x.h=(_Float16)f; return x.u; }

__device__ __forceinline__ half8 cvt8v(const float* __restrict__ p){
    f32x4 a = *(const f32x4*)p, b = *(const f32x4*)(p+4);
    half8 r;
    r[0]=(_Float16)a[0]; r[1]=(_Float16)a[1]; r[2]=(_Float16)a[2]; r[3]=(_Float16)a[3];
    r[4]=(_Float16)b[0]; r[5]=(_Float16)b[1]; r[6]=(_Float16)b[2]; r[7]=(_Float16)b[3];
    return r;
}

// Pin weight fragments into the AGPR file (opaque asm result cannot be
// rematerialized; AGPRs otherwise idle; MFMA reads A from AGPR directly).
__device__ __forceinline__ void pina(half8& v){ asm volatile("" : "+a"(v)); }
__device__ __forceinline__ void pinv(f32x4& v){ asm volatile("" : "+v"(v)); }

#define MFMA(A,B,C) __builtin_amdgcn_mfma_f32_16x16x32_f16((A),(B),(C),0,0,0)
#define ALOAD64(p)    __hip_atomic_load((p), __ATOMIC_RELAXED, __HIP_MEMORY_SCOPE_AGENT)
#define ASTORE64(p,v) __hip_atomic_store((p), (v), __ATOMIC_RELAXED, __HIP_MEMORY_SCOPE_AGENT)
#define ASTORE16(p,v) __hip_atomic_store((p), (v), __ATOMIC_RELAXED, __HIP_MEMORY_SCOPE_AGENT)

// Persistent gate-sliced, layer-pipelined 2-layer LSTM — BARRIER-FREE inner loop.
// 128 WGs x 256 thr: group=blockIdx%16 (16 batch rows), slice=blockIdx/16 (32 chans).
// Each WAVE is an independent agent owning 8 channels (1 chanblock) of both layers.
// Superstep t: compute h0(t) [t<TT] and h1(t-1) [t>0]; h fragments are loaded
// straight into MFMA B-registers from the blocked MALL buffer (no LDS staging,
// no __syncthreads). Sync: per (group,t) one 64B line of 32 u16 wave-slots.
__global__ __launch_bounds__(256,1) __attribute__((amdgpu_waves_per_eu(1)))
void lstm_pers(
    const float* __restrict__ x,
    const float* __restrict__ Wih0, const float* __restrict__ Whh0,
    const float* __restrict__ bih0, const float* __restrict__ bhh0,
    const float* __restrict__ Wih1, const float* __restrict__ Whh1,
    const float* __restrict__ bih1, const float* __restrict__ bhh1,
    const float* __restrict__ W1, const float* __restrict__ b1,
    const float* __restrict__ W2, const float* __restrict__ b2,
    unsigned short* __restrict__ flags,
    _Float16* __restrict__ hb0, _Float16* __restrict__ hb1,
    float* __restrict__ out)
{
    // per-wave store-transpose tiles (wave-local; lgkmcnt only, no barrier)
    __shared__ __align__(16) unsigned short twv[4][2][16][8];   // 2 KB
    __shared__ __align__(16) float epi[16*256 + 16*128];        // 24 KB (epilogue)

    const int tid = threadIdx.x;
    const int w   = tid >> 6;
    const int l   = tid & 63;
    const int lr  = l & 15;
    const int lk  = l >> 4;
    const int g   = blockIdx.x & (NG-1);
    const int s   = blockIdx.x >> 4;
    const int gbase = g * 16;
    const int cw  = s*32 + w*8;
    const int wid = s*4 + w;          // wave id in group == chanblock (0..31)

    // ---- resident weight fragments (MFMA A-operand), pinned into AGPRs ----
    half8 wA0[10][2];   // layer0: kt<8 -> Whh0 (K=256), kt=8,9 -> Wih0 (K=64)
    half8 wA1[16][2];   // layer1: kt<8 -> Whh1, kt>=8 -> Wih1
    f32x4 bias0v[2], bias1v[2];
#pragma unroll
    for (int m=0;m<2;++m){
        const int n = (lr&3)*HH + cw + m*4 + (lr>>2);
#pragma unroll
        for (int kt=0;kt<10;++kt){
            const float* src = (kt<8) ? (Whh0 + (size_t)n*HH + kt*32 + lk*8)
                                      : (Wih0 + (size_t)n*II + (kt-8)*32 + lk*8);
            wA0[kt][m] = cvt8v(src);
            pina(wA0[kt][m]);
        }
#pragma unroll
        for (int kt=0;kt<16;++kt){
            const float* src = (kt<8) ? (Whh1 + (size_t)n*HH + kt*32 + lk*8)
                                      : (Wih1 + (size_t)n*HH + (kt-8)*32 + lk*8);
            wA1[kt][m] = cvt8v(src);
            pina(wA1[kt][m]);
        }
        const int cD = cw + m*4 + lk;
#pragma unroll
        for (int j=0;j<4;++j){
            bias0v[m][j] = bih0[j*HH+cD] + bhh0[j*HH+cD];
            bias1v[m][j] = bih1[j*HH+cD] + bhh1[j*HH+cD];
        }
        pinv(bias0v[m]); pinv(bias1v[m]);
    }

    float c0s0=0.f, c0s1=0.f, c1s0=0.f, c1s1=0.f;
    unsigned short* fgrp = flags + (size_t)g*FST*32;

    // ---- x(0) register prefetch ----
    f32x4 xa, xb, xc, xd;
    {
        const float* xp = x + ((size_t)(gbase+lr)*TT)*II + lk*8;
        xa = *(const f32x4*)xp;      xb = *(const f32x4*)(xp+4);
        xc = *(const f32x4*)(xp+32); xd = *(const f32x4*)(xp+36);
    }

    half8 bh0[8] = {}, bh1[8] = {};   // current-step h fragments (B-operand)

    for (int t=0; t<=TT; ++t){
        f32x4 a0m0 = bias0v[0], a0m1 = bias0v[1];
        f32x4 a1m0 = bias1v[0], a1m1 = bias1v[1];

        // x-part of layer0 from prefetched registers
        if (t < TT){
            half8 bx0, bx1;
#pragma unroll
            for (int j=0;j<4;++j){
                bx0[j]   = (_Float16)xa[j];  bx0[4+j] = (_Float16)xb[j];
                bx1[j]   = (_Float16)xc[j];  bx1[4+j] = (_Float16)xd[j];
            }
            a0m0 = MFMA(wA0[8][0], bx0, a0m0);
            a0m1 = MFMA(wA0[8][1], bx0, a0m1);
            a0m0 = MFMA(wA0[9][0], bx1, a0m0);
            a0m1 = MFMA(wA0[9][1], bx1, a0m1);
        }

        if (t > 0){
            if (t < TT){
#pragma unroll
                for (int kt=0;kt<8;++kt){         // Whh0 * h0(t-1)
                    a0m0 = MFMA(wA0[kt][0], bh0[kt], a0m0);
                    a0m1 = MFMA(wA0[kt][1], bh0[kt], a0m1);
                }
            }
#pragma unroll
            for (int kt=0;kt<8;++kt){             // Wih1 * h0(t-1)
                a1m0 = MFMA(wA1[8+kt][0], bh0[kt], a1m0);
                a1m1 = MFMA(wA1[8+kt][1], bh0[kt], a1m1);
            }
            if (t >= 2){
#pragma unroll
                for (int kt=0;kt<8;++kt){         // Whh1 * h1(t-2)
                    a1m0 = MFMA(wA1[kt][0], bh1[kt], a1m0);
                    a1m1 = MFMA(wA1[kt][1], bh1[kt], a1m1);
                }
            }
        }

        // ---- activations -> wave-local LDS transpose tile ----
        if (t < TT){
            float ig=sigm(a0m0[0]), fg=sigm(a0m0[1]), gg=tanhf_(a0m0[2]), og=sigm(a0m0[3]);
            c0s0 = fg*c0s0 + ig*gg;
            twv[w][0][lr][lk]   = h2u(og*tanhf_(c0s0));
            float ig1=sigm(a0m1[0]), fg1=sigm(a0m1[1]), gg1=tanhf_(a0m1[2]), og1=sigm(a0m1[3]);
            c0s1 = fg1*c0s1 + ig1*gg1;
            twv[w][0][lr][lk+4] = h2u(og1*tanhf_(c0s1));
        }
        if (t > 0){
            float ig=sigm(a1m0[0]), fg=sigm(a1m0[1]), gg=tanhf_(a1m0[2]), og=sigm(a1m0[3]);
            c1s0 = fg*c1s0 + ig*gg;
            twv[w][1][lr][lk]   = h2u(og*tanhf_(c1s0));
            float ig1=sigm(a1m1[0]), fg1=sigm(a1m1[1]), gg1=tanhf_(a1m1[2]), og1=sigm(a1m1[3]);
            c1s1 = fg1*c1s1 + ig1*gg1;
            twv[w][1][lr][lk+4] = h2u(og1*tanhf_(c1s1));
        }
        asm volatile("s_waitcnt lgkmcnt(0)" ::: "memory");

        // x prefetch for t+1 (overlaps the store drain below)
        if (t + 1 < TT){
            const float* xp = x + ((size_t)(gbase+lr)*TT + (t+1))*II + lk*8;
            xa = *(const f32x4*)xp;      xb = *(const f32x4*)(xp+4);
            xc = *(const f32x4*)(xp+32); xd = *(const f32x4*)(xp+36);
        }

        // ---- coalesced piece stores: lanes 0..31, one u64 each, 256B/wave ----
        if (l < 32){
            if (t < TT){
                unsigned long long v = *(const unsigned long long*)&twv[w][0][l>>1][(l&1)*4];
                ASTORE64((unsigned long long*)hb0
                         + ((size_t)((t&1)*NG + g))*1024 + wid*32 + l, v);
            }
            if (t > 0){
                unsigned long long v = *(const unsigned long long*)&twv[w][1][l>>1][(l&1)*4];
                ASTORE64((unsigned long long*)hb1
                         + ((size_t)(((t-1)&1)*NG + g))*1024 + wid*32 + l, v);
            }
        }
        asm volatile("s_waitcnt vmcnt(0)" ::: "memory");   // pieces globally visible
        if (l == 0)
            ASTORE16(&fgrp[t*32 + wid], (unsigned short)(t+1));

        if (t < TT){
            // ---- poll the group line: 32 slots == t+1 ----
            const unsigned long long pat =
                0x0001000100010001ULL * (unsigned long long)(t+1);
            const unsigned long long* fp = (const unsigned long long*)(fgrp + t*32);
            for (;;){
                unsigned long long v = (l < 8) ? ALOAD64(fp + l) : pat;
                if (__all(v == pat)) break;
            }
            // ---- load next-step fragments straight into B-registers ----
            const unsigned long long* H0 = (const unsigned long long*)hb0
                + ((size_t)((t&1)*NG + g))*1024;
#pragma unroll
            for (int kt=0;kt<8;++kt){
                const int idx = ((kt*4 + lk)*16 + lr)*2;
                unsigned long long a = ALOAD64(H0 + idx);
                unsigned long long b = ALOAD64(H0 + idx + 1);
                union { unsigned long long u[2]; half8 h; } cv;
                cv.u[0] = a; cv.u[1] = b;
                bh0[kt] = cv.h;
            }
            if (t >= 1){
                const unsigned long long* H1 = (const unsigned long long*)hb1
                    + ((size_t)(((t+1)&1)*NG + g))*1024;
#pragma unroll
                for (int kt=0;kt<8;++kt){
                    const int idx = ((kt*4 + lk)*16 + lr)*2;
                    unsigned long long a = ALOAD64(H1 + idx);
                    unsigned long long b = ALOAD64(H1 + idx + 1);
                    union { unsigned long long u[2]; half8 h; } cv;
                    cv.u[0] = a; cv.u[1] = b;
                    bh1[kt] = cv.h;
                }
            }
        }
    }

    // ---- epilogue: slice 0 of each group computes the MLP head ----
    if (s == 0){
        {   // ensure all h1(TT-1) pieces are visible
            const unsigned long long pat =
                0x0001000100010001ULL * (unsigned long long)(TT+1);
            const unsigned long long* fp = (const unsigned long long*)(fgrp + TT*32);
            for (;;){
                unsigned long long v = (l < 8) ? ALOAD64(fp + l) : pat;
                if (__all(v == pat)) break;
            }
        }
        __syncthreads();
        float* hl  = epi;              // [16][256]
        float* zsh = epi + 16*256;     // [16][128]
        const unsigned long long* HL = (const unsigned long long*)hb1
            + ((size_t)(((TT-1)&1)*NG + g))*1024;
        for (int i = tid; i < 1024; i += 256){
            const int r = i >> 6, q = i & 63;
            const size_t gi = (size_t)(q>>1)*32 + r*2 + (q&1);
            unsigned long long v = ALOAD64(HL + gi);
            union { unsigned long long u; _Float16 h[4]; } cv; cv.u = v;
#pragma unroll
            for (int e=0;e<4;++e) hl[r*256 + q*4 + e] = (float)cv.h[e];
        }
        __syncthreads();
        for (int idx = tid; idx < 2048; idx += 256){
            const int r = idx >> 7, j = idx & 127;
            const float* wrow = W1 + j*HH;
            const float* hr = hl + r*256;
            float ssum = b1[j];
            for (int k=0;k<HH;k+=4){
                f32x4 wv = *(const f32x4*)(wrow + k);
                ssum += hr[k]*wv[0] + hr[k+1]*wv[1] + hr[k+2]*wv[2] + hr[k+3]*wv[3];
            }
            zsh[r*128 + j] = tanhf_(ssum);
        }
        __syncthreads();
        for (int idx = tid; idx < 1536; idx += 256){
            const int r = idx / 96, o = idx - r*96;
            const float* wrow = W2 + o*128;
            const float* zr = zsh + r*128;
            float ssum = b2[o];
            for (int k=0;k<128;k+=4){
                f32x4 wv = *(const f32x4*)(wrow + k);
                ssum += zr[k]*wv[0] + zr[k+1]*wv[1] + zr[k+2]*wv[2] + zr[k+3]*wv[3];
            }
            out[(size_t)(gbase+r)*96 + o] = ssum;
        }
    }
}

extern "C" void kernel_launch(void* const* d_in, const int* in_sizes, int n_in,
                              void* d_out, int out_size, void* d_ws, size_t ws_size,
                              hipStream_t stream) {
    const float* x    = (const float*)d_in[0];
    const float* Wih0 = (const float*)d_in[1];
    const float* Whh0 = (const float*)d_in[2];
    const float* bih0 = (const float*)d_in[3];
    const float* bhh0 = (const float*)d_in[4];
    const float* Wih1 = (const float*)d_in[5];
    const float* Whh1 = (const float*)d_in[6];
    const float* bih1 = (const float*)d_in[7];
    const float* bhh1 = (const float*)d_in[8];
    const float* W1   = (const float*)d_in[9];
    const float* b1   = (const float*)d_in[10];
    const float* W2   = (const float*)d_in[11];
    const float* b2   = (const float*)d_in[12];

    // workspace: flags 16*520*64 B = 532,480 (zeroed per call)
    //            hb0/hb1 blocked: 2 bufs * 16 g * 32 blk * 256 B = 262,144 B each
    unsigned short* flags = (unsigned short*)d_ws;
    _Float16* hb0 = (_Float16*)((char*)d_ws + 532480);
    _Float16* hb1 = (_Float16*)((char*)d_ws + 532480 + 262144);

    hipMemsetAsync(d_ws, 0, 532480, stream);

    hipLaunchKernelGGL(lstm_pers, dim3(NG*NS), dim3(256), 0, stream,
                       x, Wih0, Whh0, bih0, bhh0,
                       Wih1, Whh1, bih1, bhh1,
                       W1, b1, W2, b2,
                       flags, hb0, hb1, (float*)d_out);
}